// Round 7
// baseline (209.185 us; speedup 1.0000x reference)
//
#include <hip/hip_runtime.h>
#include <hip/hip_bf16.h>
#include <math.h>

#define B_ 4
#define T_ 2048
#define DM 768
#define H_ 12
#define DH 64

typedef __attribute__((ext_vector_type(4))) float f32x4;
typedef __attribute__((ext_vector_type(8))) short s16x8;

typedef const __attribute__((address_space(1))) void* gas1_t;
typedef __attribute__((address_space(3))) void* las3_t;

__device__ __forceinline__ ushort f2b(float f) {
  union { float f; unsigned u; } v; v.f = f;
  unsigned u = v.u;
  u += 0x7fffu + ((u >> 16) & 1u);
  return (ushort)(u >> 16);
}
// packed f32x2 -> bf16x2 (RNE, same rounding as f2b) in one instruction
__device__ __forceinline__ unsigned cvt_pk_bf16(float lo, float hi) {
  unsigned r;
  asm("v_cvt_pk_bf16_f32 %0, %1, %2" : "=v"(r) : "v"(lo), "v"(hi));
  return r;
}

// ---------------- fused fp32->bf16 conversions + rope pack, one launch ----------------
__global__ void cvt_all(const float* __restrict__ x,
                        const float* __restrict__ wq, const float* __restrict__ wk,
                        const float* __restrict__ wv, const float* __restrict__ wo,
                        const float* __restrict__ rc, const float* __restrict__ rs,
                        ushort* __restrict__ xb, ushort* __restrict__ wqkv,
                        ushort* __restrict__ wob, float2* __restrict__ cs2) {
  const int bid = blockIdx.x, t = threadIdx.x;
  if (bid < 6144) {
    int i = bid * 256 + t;
    float4 v = ((const float4*)x)[i];
    ushort4 o;
    o.x = f2b(v.x); o.y = f2b(v.y); o.z = f2b(v.z); o.w = f2b(v.w);
    ((ushort4*)xb)[i] = o;
  } else if (bid < 8448) {
    int i = (bid - 6144) * 256 + t;  // 0 .. 589823
    int which = i / 147456, j = i - which * 147456;
    const float* src = which == 0 ? wq : which == 1 ? wk : which == 2 ? wv : wo;
    ushort* dst = which < 3 ? wqkv + (size_t)which * 589824 : wob;
    float4 v = ((const float4*)src)[j];
    ushort4 o;
    o.x = f2b(v.x); o.y = f2b(v.y); o.z = f2b(v.z); o.w = f2b(v.w);
    ((ushort4*)dst)[j] = o;
  } else {
    int i = (bid - 8448) * 256 + t;  // 0 .. 65535
    cs2[i] = make_float2(rc[i], rs[i]);
  }
}

// ---------------- QKV GEMM: 128x192 tiles, BK=64, grid 768 = 3/CU exact ----------------
// 768 = 8 XCD x 8 m-panels x 12 n-panels(192). 48 MFMA per barrier pair.
__global__ __launch_bounds__(256, 3) void gemm_qkv(
    const ushort* __restrict__ A, const ushort* __restrict__ Bw,
    const float2* __restrict__ cs2,
    ushort* __restrict__ Qb, ushort* __restrict__ Kb, ushort* __restrict__ Vt) {
  const int K = 768;
  __shared__ ushort As[128 * 64];
  __shared__ ushort Bs[192 * 64];
  const int bid = blockIdx.x;
  const int xcd = bid & 7;
  const int jj = bid >> 3;               // 0..95
  const int mloc = jj / 12, nn0 = jj - mloc * 12;
  const int m0 = (xcd * 8 + mloc) * 128, n0 = nn0 * 192;
  const int tid = threadIdx.x;
  const int wave = tid >> 6, lane = tid & 63;
  const int wm = (wave >> 1) * 64, wn = (wave & 1) * 96;
  const int quad = lane >> 4, l16 = lane & 15;
  const int tr = tid >> 3;                 // staging row 0..31 (per 32-row pass)
  const int scb = (tid & 7) ^ (tr & 7);    // pre-swizzled source colblock
  const int swz = l16 & 7;                 // frag-read swizzle term (= row&7)

  f32x4 acc[4][6] = {};

  const ushort* ga = A + (size_t)(m0 + tr) * K + scb * 8;
  const ushort* gb = Bw + (size_t)(n0 + tr) * K + scb * 8;

  for (int k0 = 0; k0 < K; k0 += 64) {
#pragma unroll
    for (int p = 0; p < 4; p++)
      __builtin_amdgcn_global_load_lds((gas1_t)(ga + (size_t)(p * 32) * K + k0),
                                       (las3_t)(As + p * 2048 + tid * 8), 16, 0, 0);
#pragma unroll
    for (int p = 0; p < 6; p++)
      __builtin_amdgcn_global_load_lds((gas1_t)(gb + (size_t)(p * 32) * K + k0),
                                       (las3_t)(Bs + p * 2048 + tid * 8), 16, 0, 0);
    __syncthreads();
#pragma unroll
    for (int kk = 0; kk < 2; kk++) {
      s16x8 af[4], bf[6];
#pragma unroll
      for (int i = 0; i < 4; i++) {
        const ushort* ar = As + (wm + i * 16 + l16) * 64;
        af[i] = *(const s16x8*)(ar + (((kk * 4 + quad) ^ swz) * 8));
      }
#pragma unroll
      for (int n = 0; n < 6; n++) {
        const ushort* br = Bs + (wn + n * 16 + l16) * 64;
        bf[n] = *(const s16x8*)(br + (((kk * 4 + quad) ^ swz) * 8));
      }
#pragma unroll
      for (int i = 0; i < 4; i++)
#pragma unroll
        for (int n = 0; n < 6; n++)
          acc[i][n] = __builtin_amdgcn_mfma_f32_16x16x32_bf16(af[i], bf[n], acc[i][n], 0, 0, 0);
    }
    __syncthreads();
  }

  const int sec = n0 / 768;  // 0=q, 1=k, 2=v (uniform per block; 768 = 4*192)
  if (sec < 2) {
    ushort* dst = sec == 0 ? Qb : Kb;
#pragma unroll
    for (int i = 0; i < 4; i++) {
      int row0 = m0 + wm + i * 16 + quad * 4;
#pragma unroll
      for (int nt = 0; nt < 6; nt++) {
        int col = n0 + wn + nt * 16 + l16;
        int nv = col - sec * 768;
        int h = nv >> 6, d = nv & 63;
        int ip = (d >> 1) & 31;
        float sgn = (d & 1) ? 1.f : -1.f;
#pragma unroll
        for (int r = 0; r < 4; r++) {
          int rrow = row0 + r;
          int t = rrow & (T_ - 1), bb = rrow >> 11;
          float v = acc[i][nt][r];
          float partner = __shfl_xor(v, 1);
          float2 cs = cs2[t * 32 + ip];
          float out = fmaf(v, cs.x, sgn * partner * cs.y);
          dst[((size_t)(bb * H_ + h) * T_ + t) * DH + d] = f2b(out);
        }
      }
    }
  } else {
#pragma unroll
    for (int i = 0; i < 4; i++) {
      int row0 = m0 + wm + i * 16 + quad * 4;
      int t0 = row0 & (T_ - 1), b = row0 >> 11;  // 4 rows share b (aligned)
#pragma unroll
      for (int nt = 0; nt < 6; nt++) {
        int col = n0 + wn + nt * 16 + l16;
        int nv = col - 1536;
        int h = nv >> 6, d = nv & 63;
        ushort4 pk;
        pk.x = f2b(acc[i][nt][0]); pk.y = f2b(acc[i][nt][1]);
        pk.z = f2b(acc[i][nt][2]); pk.w = f2b(acc[i][nt][3]);
        *(ushort4*)(Vt + ((size_t)(b * H_ + h) * DH + d) * T_ + t0) = pk;
      }
    }
  }
}

// ---------------- output GEMM: 128x96 tiles, BK=64, grid 512 = 2/CU exact ----------------
// 512 = 8 XCD x 8 m x 8 n(96).
__global__ __launch_bounds__(256, 3) void gemm_out(
    const ushort* __restrict__ A, const ushort* __restrict__ Bw, float* __restrict__ C) {
  const int K = 768, N = 768;
  __shared__ ushort As[128 * 64];
  __shared__ ushort Bs[96 * 64];
  const int bid = blockIdx.x;
  const int xcd = bid & 7;
  const int jj = bid >> 3;               // 0..63
  const int mloc = jj >> 3, nn0 = jj & 7;
  const int m0 = (xcd * 8 + mloc) * 128, n0 = nn0 * 96;
  const int tid = threadIdx.x;
  const int wave = tid >> 6, lane = tid & 63;
  const int wm = (wave >> 1) * 64, wn = (wave & 1) * 48;
  const int quad = lane >> 4, l16 = lane & 15;
  const int tr = tid >> 3;
  const int scb = (tid & 7) ^ (tr & 7);
  const int swz = l16 & 7;

  f32x4 acc[4][3] = {};

  const ushort* ga = A + (size_t)(m0 + tr) * K + scb * 8;
  const ushort* gb = Bw + (size_t)(n0 + tr) * K + scb * 8;

  for (int k0 = 0; k0 < K; k0 += 64) {
#pragma unroll
    for (int p = 0; p < 4; p++)
      __builtin_amdgcn_global_load_lds((gas1_t)(ga + (size_t)(p * 32) * K + k0),
                                       (las3_t)(As + p * 2048 + tid * 8), 16, 0, 0);
#pragma unroll
    for (int p = 0; p < 3; p++)
      __builtin_amdgcn_global_load_lds((gas1_t)(gb + (size_t)(p * 32) * K + k0),
                                       (las3_t)(Bs + p * 2048 + tid * 8), 16, 0, 0);
    __syncthreads();
#pragma unroll
    for (int kk = 0; kk < 2; kk++) {
      s16x8 af[4], bf[3];
#pragma unroll
      for (int i = 0; i < 4; i++) {
        const ushort* ar = As + (wm + i * 16 + l16) * 64;
        af[i] = *(const s16x8*)(ar + (((kk * 4 + quad) ^ swz) * 8));
      }
#pragma unroll
      for (int n = 0; n < 3; n++) {
        const ushort* br = Bs + (wn + n * 16 + l16) * 64;
        bf[n] = *(const s16x8*)(br + (((kk * 4 + quad) ^ swz) * 8));
      }
#pragma unroll
      for (int i = 0; i < 4; i++)
#pragma unroll
        for (int n = 0; n < 3; n++)
          acc[i][n] = __builtin_amdgcn_mfma_f32_16x16x32_bf16(af[i], bf[n], acc[i][n], 0, 0, 0);
    }
    __syncthreads();
  }

#pragma unroll
  for (int i = 0; i < 4; i++) {
    int row = m0 + wm + i * 16 + quad * 4;
#pragma unroll
    for (int n = 0; n < 3; n++) {
      int col = n0 + wn + n * 16 + l16;
#pragma unroll
      for (int r = 0; r < 4; r++)
        C[(size_t)(row + r) * N + col] = acc[i][n][r];
    }
  }
}

// ---------------- causal flash attention v12: swizzled P + swapped PV ----------------
// P pitch-64 with XOR swizzle col^((l16&7)<<3) (round-2-verified pattern, bits
// >=3 only -> k-order inside b128 reads preserved); writes as b32 pairs (2/bank
// = free). Swapped PV: o = mfma(V^T, P) -> O^T layout, rsum lane-local, 8B
// vectorized Ob stores. LDS exactly 40960 B. No setprio.
#define EXP2SCALE 0.18033688f   /* 0.125 * log2(e) */
#define EXP2OFF  17.312340f     /* 12 * log2(e) */
__global__ __launch_bounds__(256, 3) void attn(const ushort* __restrict__ Qb, const ushort* __restrict__ Kb,
                                               const ushort* __restrict__ Vt, ushort* __restrict__ Ob) {
  const int bh = blockIdx.x;
  const int p = blockIdx.y;        // pair index 0..15
  const int tid = threadIdx.x, wave = tid >> 6, lane = tid & 63;
  const int quad = lane >> 4, l16 = lane & 15;
  const int b = bh / H_, h = bh % H_;
  const ushort* Qp = Qb + (size_t)bh * T_ * DH;
  const ushort* Kp = Kb + (size_t)bh * T_ * DH;
  const ushort* Vp = Vt + (size_t)bh * DH * T_;

  __shared__ ushort Ks[2][64 * 64];
  __shared__ ushort Vs[2][64 * 64];
  __shared__ ushort P[4][16][64];   // per wave; row = q (l16), col XOR-swizzled

  const int myTile = (wave < 2) ? p : (31 - p);     // 64-row q tile
  const int qbase0 = myTile * 64 + (wave & 1) * 32; // this wave's 32 rows

  s16x8 aq[2][2];
#pragma unroll
  for (int m = 0; m < 2; m++) {
    const ushort* qp = Qp + (size_t)(qbase0 + m * 16 + l16) * DH + quad * 8;
    aq[m][0] = *(const s16x8*)qp;
    aq[m][1] = *(const s16x8*)(qp + 32);
  }
  f32x4 o[2][4] = {};
  float rsum[2] = {0.f, 0.f};

  const int ntile = 32 - p;
  const int srow = tid >> 3;                   // 0..31
  const int scbK = (tid & 7) ^ (srow & 7);     // swizzled source colblock
  const int swz = (l16 & 7);
  const int psw = swz << 3;                    // P column swizzle term

  {
    const int kv0 = 0;
    __builtin_amdgcn_global_load_lds((gas1_t)(Kp + (size_t)(kv0 + srow) * DH + scbK * 8),
                                     (las3_t)(Ks[0] + tid * 8), 16, 0, 0);
    __builtin_amdgcn_global_load_lds((gas1_t)(Kp + (size_t)(kv0 + srow + 32) * DH + scbK * 8),
                                     (las3_t)(Ks[0] + 2048 + tid * 8), 16, 0, 0);
    __builtin_amdgcn_global_load_lds((gas1_t)(Vp + (size_t)srow * T_ + kv0 + scbK * 8),
                                     (las3_t)(Vs[0] + tid * 8), 16, 0, 0);
    __builtin_amdgcn_global_load_lds((gas1_t)(Vp + (size_t)(srow + 32) * T_ + kv0 + scbK * 8),
                                     (las3_t)(Vs[0] + 2048 + tid * 8), 16, 0, 0);
  }

  for (int c = 0; c < ntile; c++) {
    const int kv0 = c * 64;
    const int cur = c & 1;
    __syncthreads();  // drains own vmcnt -> buf[cur] staged & visible
    if (c + 1 < ntile) {
      const int kv1 = kv0 + 64, nxt = cur ^ 1;
      __builtin_amdgcn_global_load_lds((gas1_t)(Kp + (size_t)(kv1 + srow) * DH + scbK * 8),
                                       (las3_t)(Ks[nxt] + tid * 8), 16, 0, 0);
      __builtin_amdgcn_global_load_lds((gas1_t)(Kp + (size_t)(kv1 + srow + 32) * DH + scbK * 8),
                                       (las3_t)(Ks[nxt] + 2048 + tid * 8), 16, 0, 0);
      __builtin_amdgcn_global_load_lds((gas1_t)(Vp + (size_t)srow * T_ + kv1 + scbK * 8),
                                       (las3_t)(Vs[nxt] + tid * 8), 16, 0, 0);
      __builtin_amdgcn_global_load_lds((gas1_t)(Vp + (size_t)(srow + 32) * T_ + kv1 + scbK * 8),
                                       (las3_t)(Vs[nxt] + 2048 + tid * 8), 16, 0, 0);
    }

    if (kv0 <= qbase0 + 31) {
      s16x8 kf[4][2];
#pragma unroll
      for (int nt = 0; nt < 4; nt++) {
        const ushort* kr = Ks[cur] + (nt * 16 + l16) * 64;
        kf[nt][0] = *(const s16x8*)(kr + ((quad ^ swz) * 8));
        kf[nt][1] = *(const s16x8*)(kr + (((4 + quad) ^ swz) * 8));
      }
      s16x8 bv[4][2];
#pragma unroll
      for (int dt = 0; dt < 4; dt++) {
        const ushort* vr = Vs[cur] + (dt * 16 + l16) * 64;
        bv[dt][0] = *(const s16x8*)(vr + ((quad ^ swz) * 8));
        bv[dt][1] = *(const s16x8*)(vr + (((4 + quad) ^ swz) * 8));
      }

#pragma unroll
      for (int m = 0; m < 2; m++) {
        const int qb = qbase0 + m * 16;
        if (kv0 > qb + 15) continue;  // fully masked frag (wave-uniform)
        // S^T: rows = kv (quad*4+r within nt), cols = q (l16)
        f32x4 s[4] = {};
#pragma unroll
        for (int nt = 0; nt < 4; nt++) {
          s[nt] = __builtin_amdgcn_mfma_f32_16x16x32_bf16(kf[nt][0], aq[m][0], s[nt], 0, 0, 0);
          s[nt] = __builtin_amdgcn_mfma_f32_16x16x32_bf16(kf[nt][1], aq[m][1], s[nt], 0, 0, 0);
        }
        if (kv0 + 63 <= qb) {  // fully unmasked
#pragma unroll
          for (int nt = 0; nt < 4; nt++) {
            float p0 = __builtin_amdgcn_exp2f(fmaf(s[nt][0], EXP2SCALE, -EXP2OFF));
            float p1 = __builtin_amdgcn_exp2f(fmaf(s[nt][1], EXP2SCALE, -EXP2OFF));
            float p2 = __builtin_amdgcn_exp2f(fmaf(s[nt][2], EXP2SCALE, -EXP2OFF));
            float p3 = __builtin_amdgcn_exp2f(fmaf(s[nt][3], EXP2SCALE, -EXP2OFF));
            rsum[m] += (p0 + p1) + (p2 + p3);
            int sc = (nt * 16 + quad * 4) ^ psw;
            *(unsigned*)&P[wave][l16][sc] = cvt_pk_bf16(p0, p1);
            *(unsigned*)&P[wave][l16][sc + 2] = cvt_pk_bf16(p2, p3);
          }
        } else {  // diagonal tile: mask kv > qi (qi = qb + l16)
          int qi = qb + l16;
#pragma unroll
          for (int nt = 0; nt < 4; nt++) {
            int kvb = kv0 + nt * 16 + quad * 4;
            float pv[4];
#pragma unroll
            for (int r = 0; r < 4; r++)
              pv[r] = (kvb + r <= qi) ? __builtin_amdgcn_exp2f(fmaf(s[nt][r], EXP2SCALE, -EXP2OFF)) : 0.f;
            rsum[m] += (pv[0] + pv[1]) + (pv[2] + pv[3]);
            int sc = (nt * 16 + quad * 4) ^ psw;
            *(unsigned*)&P[wave][l16][sc] = cvt_pk_bf16(pv[0], pv[1]);
            *(unsigned*)&P[wave][l16][sc + 2] = cvt_pk_bf16(pv[2], pv[3]);
          }
        }
        s16x8 ap0 = *(const s16x8*)&P[wave][l16][(quad * 8) ^ psw];
        s16x8 ap1 = *(const s16x8*)&P[wave][l16][(32 + quad * 8) ^ psw];
        // swapped PV: O^T[d][q] = V^T x P^T  (A/B frags have identical layouts)
#pragma unroll
        for (int dt = 0; dt < 4; dt++) {
          o[m][dt] = __builtin_amdgcn_mfma_f32_16x16x32_bf16(bv[dt][0], ap0, o[m][dt], 0, 0, 0);
          o[m][dt] = __builtin_amdgcn_mfma_f32_16x16x32_bf16(bv[dt][1], ap1, o[m][dt], 0, 0, 0);
        }
      }
    }
  }
  // rsum[m]: partial over this lane's quad kv-slice for q=l16 -> sum quads.
#pragma unroll
  for (int m = 0; m < 2; m++) {
    rsum[m] += __shfl_xor(rsum[m], 16);
    rsum[m] += __shfl_xor(rsum[m], 32);
  }
#pragma unroll
  for (int m = 0; m < 2; m++) {
    float inv = 1.0f / rsum[m];
    int q = qbase0 + m * 16 + l16;
    size_t base = (size_t)(b * T_ + q) * DM + h * 64 + quad * 4;
#pragma unroll
    for (int dt = 0; dt < 4; dt++) {
      ushort4 pk4;
      pk4.x = f2b(o[m][dt][0] * inv); pk4.y = f2b(o[m][dt][1] * inv);
      pk4.z = f2b(o[m][dt][2] * inv); pk4.w = f2b(o[m][dt][3] * inv);
      *(ushort4*)&Ob[base + dt * 16] = pk4;
    }
  }
}

extern "C" void kernel_launch(void* const* d_in, const int* in_sizes, int n_in,
                              void* d_out, int out_size, void* d_ws, size_t ws_size,
                              hipStream_t stream) {
  const float* x = (const float*)d_in[0];
  const float* rc = (const float*)d_in[1];
  const float* rs = (const float*)d_in[2];
  const float* wq = (const float*)d_in[3];
  const float* wk = (const float*)d_in[4];
  const float* wv = (const float*)d_in[5];
  const float* wo = (const float*)d_in[6];

  char* ws = (char*)d_ws;
  ushort* xb   = (ushort*)(ws);                 // 12,582,912
  ushort* wqkv = (ushort*)(ws + 12582912);      //  3,538,944
  ushort* wob  = (ushort*)(ws + 16121856);      //  1,179,648
  float2* cs2  = (float2*)(ws + 17301504);      //    524,288
  ushort* Qb   = (ushort*)(ws + 17825792);      // 12,582,912
  ushort* Kb   = (ushort*)(ws + 30408704);      // 12,582,912
  ushort* Vt   = (ushort*)(ws + 42991616);      // 12,582,912
  ushort* Ob   = (ushort*)(ws + 55574528);      // 12,582,912 (ends ~68.2MB)

  cvt_all<<<8704, 256, 0, stream>>>(x, wq, wk, wv, wo, rc, rs, xb, wqkv, wob, cs2);

  gemm_qkv<<<768, 256, 0, stream>>>(xb, wqkv, cs2, Qb, Kb, Vt);

  attn<<<dim3(48, 16), 256, 0, stream>>>(Qb, Kb, Vt, Ob);

  gemm_out<<<512, 256, 0, stream>>>(Ob, wob, (float*)d_out);
}

// Round 8
// 183.827 us; speedup vs baseline: 1.1379x; 1.1379x over previous
//
#include <hip/hip_runtime.h>
#include <hip/hip_bf16.h>
#include <math.h>

#define B_ 4
#define T_ 2048
#define DM 768
#define H_ 12
#define DH 64

typedef __attribute__((ext_vector_type(4))) float f32x4;
typedef __attribute__((ext_vector_type(8))) short s16x8;

typedef const __attribute__((address_space(1))) void* gas1_t;
typedef __attribute__((address_space(3))) void* las3_t;

__device__ __forceinline__ ushort f2b(float f) {
  union { float f; unsigned u; } v; v.f = f;
  unsigned u = v.u;
  u += 0x7fffu + ((u >> 16) & 1u);
  return (ushort)(u >> 16);
}
// packed f32x2 -> bf16x2 (RNE, same rounding as f2b) in one instruction
__device__ __forceinline__ unsigned cvt_pk_bf16(float lo, float hi) {
  unsigned r;
  asm("v_cvt_pk_bf16_f32 %0, %1, %2" : "=v"(r) : "v"(lo), "v"(hi));
  return r;
}

// ---------------- fused fp32->bf16 conversions + rope pack, one launch ----------------
__global__ void cvt_all(const float* __restrict__ x,
                        const float* __restrict__ wq, const float* __restrict__ wk,
                        const float* __restrict__ wv, const float* __restrict__ wo,
                        const float* __restrict__ rc, const float* __restrict__ rs,
                        ushort* __restrict__ xb, ushort* __restrict__ wqkv,
                        ushort* __restrict__ wob, float2* __restrict__ cs2) {
  const int bid = blockIdx.x, t = threadIdx.x;
  if (bid < 6144) {
    int i = bid * 256 + t;
    float4 v = ((const float4*)x)[i];
    ushort4 o;
    o.x = f2b(v.x); o.y = f2b(v.y); o.z = f2b(v.z); o.w = f2b(v.w);
    ((ushort4*)xb)[i] = o;
  } else if (bid < 8448) {
    int i = (bid - 6144) * 256 + t;  // 0 .. 589823
    int which = i / 147456, j = i - which * 147456;
    const float* src = which == 0 ? wq : which == 1 ? wk : which == 2 ? wv : wo;
    ushort* dst = which < 3 ? wqkv + (size_t)which * 589824 : wob;
    float4 v = ((const float4*)src)[j];
    ushort4 o;
    o.x = f2b(v.x); o.y = f2b(v.y); o.z = f2b(v.z); o.w = f2b(v.w);
    ((ushort4*)dst)[j] = o;
  } else {
    int i = (bid - 8448) * 256 + t;  // 0 .. 65535
    cs2[i] = make_float2(rc[i], rs[i]);
  }
}

// ---------------- QKV GEMM: 128x192 tiles, BK=64, grid 768 = 3/CU exact ----------------
// 768 = 8 XCD x 8 m-panels x 12 n-panels(192). 48 MFMA per barrier pair.
__global__ __launch_bounds__(256, 3) void gemm_qkv(
    const ushort* __restrict__ A, const ushort* __restrict__ Bw,
    const float2* __restrict__ cs2,
    ushort* __restrict__ Qb, ushort* __restrict__ Kb, ushort* __restrict__ Vt) {
  const int K = 768;
  __shared__ ushort As[128 * 64];
  __shared__ ushort Bs[192 * 64];
  const int bid = blockIdx.x;
  const int xcd = bid & 7;
  const int jj = bid >> 3;               // 0..95
  const int mloc = jj / 12, nn0 = jj - mloc * 12;
  const int m0 = (xcd * 8 + mloc) * 128, n0 = nn0 * 192;
  const int tid = threadIdx.x;
  const int wave = tid >> 6, lane = tid & 63;
  const int wm = (wave >> 1) * 64, wn = (wave & 1) * 96;
  const int quad = lane >> 4, l16 = lane & 15;
  const int tr = tid >> 3;                 // staging row 0..31 (per 32-row pass)
  const int scb = (tid & 7) ^ (tr & 7);    // pre-swizzled source colblock
  const int swz = l16 & 7;                 // frag-read swizzle term (= row&7)

  f32x4 acc[4][6] = {};

  const ushort* ga = A + (size_t)(m0 + tr) * K + scb * 8;
  const ushort* gb = Bw + (size_t)(n0 + tr) * K + scb * 8;

  for (int k0 = 0; k0 < K; k0 += 64) {
#pragma unroll
    for (int p = 0; p < 4; p++)
      __builtin_amdgcn_global_load_lds((gas1_t)(ga + (size_t)(p * 32) * K + k0),
                                       (las3_t)(As + p * 2048 + tid * 8), 16, 0, 0);
#pragma unroll
    for (int p = 0; p < 6; p++)
      __builtin_amdgcn_global_load_lds((gas1_t)(gb + (size_t)(p * 32) * K + k0),
                                       (las3_t)(Bs + p * 2048 + tid * 8), 16, 0, 0);
    __syncthreads();
#pragma unroll
    for (int kk = 0; kk < 2; kk++) {
      s16x8 af[4], bf[6];
#pragma unroll
      for (int i = 0; i < 4; i++) {
        const ushort* ar = As + (wm + i * 16 + l16) * 64;
        af[i] = *(const s16x8*)(ar + (((kk * 4 + quad) ^ swz) * 8));
      }
#pragma unroll
      for (int n = 0; n < 6; n++) {
        const ushort* br = Bs + (wn + n * 16 + l16) * 64;
        bf[n] = *(const s16x8*)(br + (((kk * 4 + quad) ^ swz) * 8));
      }
#pragma unroll
      for (int i = 0; i < 4; i++)
#pragma unroll
        for (int n = 0; n < 6; n++)
          acc[i][n] = __builtin_amdgcn_mfma_f32_16x16x32_bf16(af[i], bf[n], acc[i][n], 0, 0, 0);
    }
    __syncthreads();
  }

  const int sec = n0 / 768;  // 0=q, 1=k, 2=v (uniform per block; 768 = 4*192)
  if (sec < 2) {
    ushort* dst = sec == 0 ? Qb : Kb;
#pragma unroll
    for (int i = 0; i < 4; i++) {
      int row0 = m0 + wm + i * 16 + quad * 4;
#pragma unroll
      for (int nt = 0; nt < 6; nt++) {
        int col = n0 + wn + nt * 16 + l16;
        int nv = col - sec * 768;
        int h = nv >> 6, d = nv & 63;
        int ip = (d >> 1) & 31;
        float sgn = (d & 1) ? 1.f : -1.f;
#pragma unroll
        for (int r = 0; r < 4; r++) {
          int rrow = row0 + r;
          int t = rrow & (T_ - 1), bb = rrow >> 11;
          float v = acc[i][nt][r];
          float partner = __shfl_xor(v, 1);
          float2 cs = cs2[t * 32 + ip];
          float out = fmaf(v, cs.x, sgn * partner * cs.y);
          dst[((size_t)(bb * H_ + h) * T_ + t) * DH + d] = f2b(out);
        }
      }
    }
  } else {
#pragma unroll
    for (int i = 0; i < 4; i++) {
      int row0 = m0 + wm + i * 16 + quad * 4;
      int t0 = row0 & (T_ - 1), b = row0 >> 11;  // 4 rows share b (aligned)
#pragma unroll
      for (int nt = 0; nt < 6; nt++) {
        int col = n0 + wn + nt * 16 + l16;
        int nv = col - 1536;
        int h = nv >> 6, d = nv & 63;
        ushort4 pk;
        pk.x = f2b(acc[i][nt][0]); pk.y = f2b(acc[i][nt][1]);
        pk.z = f2b(acc[i][nt][2]); pk.w = f2b(acc[i][nt][3]);
        *(ushort4*)(Vt + ((size_t)(b * H_ + h) * DH + d) * T_ + t0) = pk;
      }
    }
  }
}

// ---------------- output GEMM: 128x96 tiles, BK=64, grid 512 = 2/CU exact ----------------
// 512 = 8 XCD x 8 m x 8 n(96).
__global__ __launch_bounds__(256, 3) void gemm_out(
    const ushort* __restrict__ A, const ushort* __restrict__ Bw, float* __restrict__ C) {
  const int K = 768, N = 768;
  __shared__ ushort As[128 * 64];
  __shared__ ushort Bs[96 * 64];
  const int bid = blockIdx.x;
  const int xcd = bid & 7;
  const int jj = bid >> 3;               // 0..63
  const int mloc = jj >> 3, nn0 = jj & 7;
  const int m0 = (xcd * 8 + mloc) * 128, n0 = nn0 * 96;
  const int tid = threadIdx.x;
  const int wave = tid >> 6, lane = tid & 63;
  const int wm = (wave >> 1) * 64, wn = (wave & 1) * 48;
  const int quad = lane >> 4, l16 = lane & 15;
  const int tr = tid >> 3;
  const int scb = (tid & 7) ^ (tr & 7);
  const int swz = l16 & 7;

  f32x4 acc[4][3] = {};

  const ushort* ga = A + (size_t)(m0 + tr) * K + scb * 8;
  const ushort* gb = Bw + (size_t)(n0 + tr) * K + scb * 8;

  for (int k0 = 0; k0 < K; k0 += 64) {
#pragma unroll
    for (int p = 0; p < 4; p++)
      __builtin_amdgcn_global_load_lds((gas1_t)(ga + (size_t)(p * 32) * K + k0),
                                       (las3_t)(As + p * 2048 + tid * 8), 16, 0, 0);
#pragma unroll
    for (int p = 0; p < 3; p++)
      __builtin_amdgcn_global_load_lds((gas1_t)(gb + (size_t)(p * 32) * K + k0),
                                       (las3_t)(Bs + p * 2048 + tid * 8), 16, 0, 0);
    __syncthreads();
#pragma unroll
    for (int kk = 0; kk < 2; kk++) {
      s16x8 af[4], bf[3];
#pragma unroll
      for (int i = 0; i < 4; i++) {
        const ushort* ar = As + (wm + i * 16 + l16) * 64;
        af[i] = *(const s16x8*)(ar + (((kk * 4 + quad) ^ swz) * 8));
      }
#pragma unroll
      for (int n = 0; n < 3; n++) {
        const ushort* br = Bs + (wn + n * 16 + l16) * 64;
        bf[n] = *(const s16x8*)(br + (((kk * 4 + quad) ^ swz) * 8));
      }
#pragma unroll
      for (int i = 0; i < 4; i++)
#pragma unroll
        for (int n = 0; n < 3; n++)
          acc[i][n] = __builtin_amdgcn_mfma_f32_16x16x32_bf16(af[i], bf[n], acc[i][n], 0, 0, 0);
    }
    __syncthreads();
  }

#pragma unroll
  for (int i = 0; i < 4; i++) {
    int row = m0 + wm + i * 16 + quad * 4;
#pragma unroll
    for (int n = 0; n < 3; n++) {
      int col = n0 + wn + n * 16 + l16;
#pragma unroll
      for (int r = 0; r < 4; r++)
        C[(size_t)(row + r) * N + col] = acc[i][n][r];
    }
  }
}

// ---------------- causal flash attention v11 (measured 60 us): swapped QK^T + packed P ----------------
// S^T = mfma(K, Q): lane holds 4 consecutive kv for ONE q (=l16); P write packs
// via v_cvt_pk_bf16_f32 + one ds_write_b64 per nt. PV NON-swapped (O rows=q,
// cols=d -> row-major 32B-contiguous Ob stores; the O^T variant caused 2.3x
// HBM write amplification). P pitch-72. rsum lane-local, 2 shfl reduce.
#define EXP2SCALE 0.18033688f   /* 0.125 * log2(e) */
#define EXP2OFF  17.312340f     /* 12 * log2(e) */
__global__ __launch_bounds__(256, 3) void attn(const ushort* __restrict__ Qb, const ushort* __restrict__ Kb,
                                               const ushort* __restrict__ Vt, ushort* __restrict__ Ob) {
  const int bh = blockIdx.x;
  const int p = blockIdx.y;        // pair index 0..15
  const int tid = threadIdx.x, wave = tid >> 6, lane = tid & 63;
  const int quad = lane >> 4, l16 = lane & 15;
  const int b = bh / H_, h = bh % H_;
  const ushort* Qp = Qb + (size_t)bh * T_ * DH;
  const ushort* Kp = Kb + (size_t)bh * T_ * DH;
  const ushort* Vp = Vt + (size_t)bh * DH * T_;

  __shared__ ushort Ks[2][64 * 64];
  __shared__ ushort Vs[2][64 * 64];
  __shared__ ushort P[4][16][72];   // per wave; row = q (l16), col = kv

  const int myTile = (wave < 2) ? p : (31 - p);     // 64-row q tile
  const int qbase0 = myTile * 64 + (wave & 1) * 32; // this wave's 32 rows

  s16x8 aq[2][2];
#pragma unroll
  for (int m = 0; m < 2; m++) {
    const ushort* qp = Qp + (size_t)(qbase0 + m * 16 + l16) * DH + quad * 8;
    aq[m][0] = *(const s16x8*)qp;
    aq[m][1] = *(const s16x8*)(qp + 32);
  }
  f32x4 o[2][4] = {};
  float rsum[2] = {0.f, 0.f};

  const int ntile = 32 - p;  // kv tiles 0..31-p cover tile 31-p; tile p subsets
  const int srow = tid >> 3;                   // 0..31
  const int scbK = (tid & 7) ^ (srow & 7);     // swizzled source colblock
  const int swz = (l16 & 7);

  {
    const int kv0 = 0;
    __builtin_amdgcn_global_load_lds((gas1_t)(Kp + (size_t)(kv0 + srow) * DH + scbK * 8),
                                     (las3_t)(Ks[0] + tid * 8), 16, 0, 0);
    __builtin_amdgcn_global_load_lds((gas1_t)(Kp + (size_t)(kv0 + srow + 32) * DH + scbK * 8),
                                     (las3_t)(Ks[0] + 2048 + tid * 8), 16, 0, 0);
    __builtin_amdgcn_global_load_lds((gas1_t)(Vp + (size_t)srow * T_ + kv0 + scbK * 8),
                                     (las3_t)(Vs[0] + tid * 8), 16, 0, 0);
    __builtin_amdgcn_global_load_lds((gas1_t)(Vp + (size_t)(srow + 32) * T_ + kv0 + scbK * 8),
                                     (las3_t)(Vs[0] + 2048 + tid * 8), 16, 0, 0);
  }

  for (int c = 0; c < ntile; c++) {
    const int kv0 = c * 64;
    const int cur = c & 1;
    __syncthreads();  // drains own vmcnt -> buf[cur] staged & visible
    if (c + 1 < ntile) {
      const int kv1 = kv0 + 64, nxt = cur ^ 1;
      __builtin_amdgcn_global_load_lds((gas1_t)(Kp + (size_t)(kv1 + srow) * DH + scbK * 8),
                                       (las3_t)(Ks[nxt] + tid * 8), 16, 0, 0);
      __builtin_amdgcn_global_load_lds((gas1_t)(Kp + (size_t)(kv1 + srow + 32) * DH + scbK * 8),
                                       (las3_t)(Ks[nxt] + 2048 + tid * 8), 16, 0, 0);
      __builtin_amdgcn_global_load_lds((gas1_t)(Vp + (size_t)srow * T_ + kv1 + scbK * 8),
                                       (las3_t)(Vs[nxt] + tid * 8), 16, 0, 0);
      __builtin_amdgcn_global_load_lds((gas1_t)(Vp + (size_t)(srow + 32) * T_ + kv1 + scbK * 8),
                                       (las3_t)(Vs[nxt] + 2048 + tid * 8), 16, 0, 0);
    }

    // wave-uniform: skip frag reads + compute entirely once past this wave's diagonal
    if (kv0 <= qbase0 + 31) {
      s16x8 kf[4][2];
#pragma unroll
      for (int nt = 0; nt < 4; nt++) {
        const ushort* kr = Ks[cur] + (nt * 16 + l16) * 64;
        kf[nt][0] = *(const s16x8*)(kr + ((quad ^ swz) * 8));
        kf[nt][1] = *(const s16x8*)(kr + (((4 + quad) ^ swz) * 8));
      }
      s16x8 bv[4][2];
#pragma unroll
      for (int dt = 0; dt < 4; dt++) {
        const ushort* vr = Vs[cur] + (dt * 16 + l16) * 64;
        bv[dt][0] = *(const s16x8*)(vr + ((quad ^ swz) * 8));
        bv[dt][1] = *(const s16x8*)(vr + (((4 + quad) ^ swz) * 8));
      }

#pragma unroll
      for (int m = 0; m < 2; m++) {
        const int qb = qbase0 + m * 16;
        if (kv0 > qb + 15) continue;  // fully masked frag (wave-uniform)
        // S^T: rows = kv (quad*4+r within nt), cols = q (l16)
        f32x4 s[4] = {};
#pragma unroll
        for (int nt = 0; nt < 4; nt++) {
          s[nt] = __builtin_amdgcn_mfma_f32_16x16x32_bf16(kf[nt][0], aq[m][0], s[nt], 0, 0, 0);
          s[nt] = __builtin_amdgcn_mfma_f32_16x16x32_bf16(kf[nt][1], aq[m][1], s[nt], 0, 0, 0);
        }
        if (kv0 + 63 <= qb) {  // fully unmasked
#pragma unroll
          for (int nt = 0; nt < 4; nt++) {
            float p0 = __builtin_amdgcn_exp2f(fmaf(s[nt][0], EXP2SCALE, -EXP2OFF));
            float p1 = __builtin_amdgcn_exp2f(fmaf(s[nt][1], EXP2SCALE, -EXP2OFF));
            float p2 = __builtin_amdgcn_exp2f(fmaf(s[nt][2], EXP2SCALE, -EXP2OFF));
            float p3 = __builtin_amdgcn_exp2f(fmaf(s[nt][3], EXP2SCALE, -EXP2OFF));
            rsum[m] += (p0 + p1) + (p2 + p3);
            uint2 pk;
            pk.x = cvt_pk_bf16(p0, p1);
            pk.y = cvt_pk_bf16(p2, p3);
            *(uint2*)&P[wave][l16][nt * 16 + quad * 4] = pk;
          }
        } else {  // diagonal tile: mask kv > qi (qi = qb + l16)
          int qi = qb + l16;
#pragma unroll
          for (int nt = 0; nt < 4; nt++) {
            int kvb = kv0 + nt * 16 + quad * 4;
            float pv[4];
#pragma unroll
            for (int r = 0; r < 4; r++)
              pv[r] = (kvb + r <= qi) ? __builtin_amdgcn_exp2f(fmaf(s[nt][r], EXP2SCALE, -EXP2OFF)) : 0.f;
            rsum[m] += (pv[0] + pv[1]) + (pv[2] + pv[3]);
            uint2 pk;
            pk.x = cvt_pk_bf16(pv[0], pv[1]);
            pk.y = cvt_pk_bf16(pv[2], pv[3]);
            *(uint2*)&P[wave][l16][nt * 16 + quad * 4] = pk;
          }
        }
        s16x8 ap0 = *(const s16x8*)&P[wave][l16][quad * 8];
        s16x8 ap1 = *(const s16x8*)&P[wave][l16][32 + quad * 8];
#pragma unroll
        for (int dt = 0; dt < 4; dt++) {
          o[m][dt] = __builtin_amdgcn_mfma_f32_16x16x32_bf16(ap0, bv[dt][0], o[m][dt], 0, 0, 0);
          o[m][dt] = __builtin_amdgcn_mfma_f32_16x16x32_bf16(ap1, bv[dt][1], o[m][dt], 0, 0, 0);
        }
      }
    }
  }
  // rsum[m] holds this lane's partial (quad's kv slice) for q = l16.
  // Reduce across quads -> every lane has the full sum for its l16.
#pragma unroll
  for (int m = 0; m < 2; m++) {
    rsum[m] += __shfl_xor(rsum[m], 16);
    rsum[m] += __shfl_xor(rsum[m], 32);
  }
#pragma unroll
  for (int m = 0; m < 2; m++)
#pragma unroll
    for (int r = 0; r < 4; r++) {
      float inv = 1.0f / __shfl(rsum[m], quad * 4 + r);  // lane (quad*4+r) holds q-sub = quad*4+r
      int q = qbase0 + m * 16 + quad * 4 + r;
#pragma unroll
      for (int dt = 0; dt < 4; dt++)
        Ob[(size_t)(b * T_ + q) * DM + h * 64 + dt * 16 + l16] = f2b(o[m][dt][r] * inv);
    }
}

extern "C" void kernel_launch(void* const* d_in, const int* in_sizes, int n_in,
                              void* d_out, int out_size, void* d_ws, size_t ws_size,
                              hipStream_t stream) {
  const float* x = (const float*)d_in[0];
  const float* rc = (const float*)d_in[1];
  const float* rs = (const float*)d_in[2];
  const float* wq = (const float*)d_in[3];
  const float* wk = (const float*)d_in[4];
  const float* wv = (const float*)d_in[5];
  const float* wo = (const float*)d_in[6];

  char* ws = (char*)d_ws;
  ushort* xb   = (ushort*)(ws);                 // 12,582,912
  ushort* wqkv = (ushort*)(ws + 12582912);      //  3,538,944
  ushort* wob  = (ushort*)(ws + 16121856);      //  1,179,648
  float2* cs2  = (float2*)(ws + 17301504);      //    524,288
  ushort* Qb   = (ushort*)(ws + 17825792);      // 12,582,912
  ushort* Kb   = (ushort*)(ws + 30408704);      // 12,582,912
  ushort* Vt   = (ushort*)(ws + 42991616);      // 12,582,912
  ushort* Ob   = (ushort*)(ws + 55574528);      // 12,582,912 (ends ~68.2MB)

  cvt_all<<<8704, 256, 0, stream>>>(x, wq, wk, wv, wo, rc, rs, xb, wqkv, wob, cs2);

  gemm_qkv<<<768, 256, 0, stream>>>(xb, wqkv, cs2, Qb, Kb, Vt);

  attn<<<dim3(48, 16), 256, 0, stream>>>(Qb, Kb, Vt, Ob);

  gemm_out<<<512, 256, 0, stream>>>(Ob, wob, (float*)d_out);
}